// Round 1
// baseline (734.029 us; speedup 1.0000x reference)
//
#include <hip/hip_runtime.h>

// Problem constants
#define N_VERT 5000
#define NCOL   12288      // B*T*C_OUT reinterpreted columns
#define KPAD   5056       // 79*64: K padded (zero-filled)
#define MPAD   5120       // 20*256: M padded

#define G1_BLOCKS  15168  // 79*192 gemm1 blocks
#define CVT_BLOCKS 25280  // MPAD*(KPAD/4)/256

typedef float          f32x4   __attribute__((ext_vector_type(4)));
typedef float          f32x16  __attribute__((ext_vector_type(16)));
typedef unsigned short u16x4   __attribute__((ext_vector_type(4)));
typedef __bf16         bf16x8  __attribute__((ext_vector_type(8)));

__device__ __forceinline__ unsigned short f2bf(float f) {
  unsigned int u = __builtin_bit_cast(unsigned int, f);
  u += 0x7fffu + ((u >> 16) & 1u);   // RNE
  return (unsigned short)(u >> 16);
}

__device__ __forceinline__ void async16(const unsigned short* g, unsigned short* l) {
  __builtin_amdgcn_global_load_lds(
      (const __attribute__((address_space(1))) unsigned int*)g,
      (__attribute__((address_space(3))) unsigned int*)l, 16, 0, 0);
}

// ---------------------------------------------------------------------------
// Kernel P (merged prep): blocks [0, G1_BLOCKS) run GEMM1 (x@W -> Ht = H^T,
// bf16); blocks [G1_BLOCKS, +CVT_BLOCKS) convert F -> Fb bf16 [MPAD][KPAD].
// ---------------------------------------------------------------------------
__global__ __launch_bounds__(256) void prep(const float* __restrict__ x,
                                            const float* __restrict__ W,
                                            const float* __restrict__ F,
                                            unsigned short* __restrict__ Ht,
                                            unsigned short* __restrict__ Fb) {
  __shared__ float xt[64][68];
  __shared__ float Wl[64][68];
  const int tid = threadIdx.x;

  if (blockIdx.x >= G1_BLOCKS) {
    int idx = (blockIdx.x - G1_BLOCKS) * 256 + tid;
    int row = idx / (KPAD / 4);
    int c4  = (idx % (KPAD / 4)) * 4;
    u16x4 o;
    if (row < N_VERT && c4 < N_VERT) {
      f32x4 v = *(const f32x4*)(F + (long)row * N_VERT + c4);
      o.x = f2bf(v.x); o.y = f2bf(v.y); o.z = f2bf(v.z); o.w = f2bf(v.w);
    } else {
      o.x = 0; o.y = 0; o.z = 0; o.w = 0;
    }
    *(u16x4*)(Fb + (long)row * KPAD + c4) = o;
    return;
  }

  const int utile = blockIdx.x % 79;   // 0..78
  const int rr    = blockIdx.x / 79;   // 0..191

  for (int i = tid; i < 4096; i += 256) Wl[i >> 6][i & 63] = W[i];
  {
    int rowu = tid >> 2;
    int cb   = (tid & 3) * 16;
    long u   = (long)utile * 64 + rowu;
    bool valid = (u < N_VERT);
    const float* src = x + (u * 192 + rr) * 64;
#pragma unroll
    for (int q = 0; q < 4; ++q) {
      int col = cb + q * 4;
      f32x4 v = {0.f, 0.f, 0.f, 0.f};
      if (valid) v = *(const f32x4*)(src + col);
      xt[col + 0][rowu] = v.x;
      xt[col + 1][rowu] = v.y;
      xt[col + 2][rowu] = v.z;
      xt[col + 3][rowu] = v.w;
    }
  }
  __syncthreads();

  const int ul0 = (tid & 15) * 4;
  const int j0  = (tid >> 4) * 4;
  float acc[4][4] = {};
#pragma unroll 8
  for (int c = 0; c < 64; ++c) {
    f32x4 xv = *(const f32x4*)&xt[c][ul0];
    f32x4 wv = *(const f32x4*)&Wl[c][j0];
#pragma unroll
    for (int a = 0; a < 4; ++a)
#pragma unroll
      for (int b = 0; b < 4; ++b) acc[a][b] += xv[a] * wv[b];
  }

  long ug = (long)utile * 64 + ul0;
#pragma unroll
  for (int b = 0; b < 4; ++b) {
    long rowh = (long)rr * 64 + (j0 + b);
    u16x4 o = {f2bf(acc[0][b]), f2bf(acc[1][b]), f2bf(acc[2][b]), f2bf(acc[3][b])};
    *(u16x4*)(Ht + rowh * KPAD + ug) = o;
  }
}

// ---------------------------------------------------------------------------
// Kernel 3: GEMM2  agg = F @ H (+bias). 256x256 tile, BK=64, 8 waves,
// *** 32x32x16 MFMA *** (higher pipe ceiling than 16x16x32: 2495 vs 2176 TF,
// m119; half the MFMA instruction count for the same FLOPs). Same 3-phase /
// 3-barrier schedule and staging as the 16x16 version:
//  PH0: read afL(ks0,1)+bh(t); 16 MFMA afL x bl; bar
//  PH1: read afH(ks2,3); stage B(t+2); 8 MFMA afH(ks2) x bh(ks2); bar
//  PH2: stage A(t+2); vmcnt(8); bar; bl(t+1) cross-read; 8 MFMA afH(ks3)xbh(ks3)
// Hazards identical to the 16x16 version: each region's last read completes
// before its own phase's MFMA (in-order lgkmcnt), trailing barrier globalizes
// before the DMA staging targets the region (B last read: bh@PH0 -> stage@PH1;
// A last read: afH@PH1 -> stage@PH2). vmcnt(8)+bar globalizes tile t+1 before
// the bl cross-read.
// Fragment layouts (32x32x16 bf16): A/B lane l -> row/col = l&31, k-half =
// l>>5 (8 contiguous bf16); C/D col = l&31, row = (reg&3)+8*(reg>>2)+4*(l>>5).
// Read swizzle: 16B chunk index (ks*2 + (l>>5)) ^ (row&7) — store-side
// pre-swizzle unchanged (chunk ^= row&7 within 8-row groups).
// ---------------------------------------------------------------------------
__global__ __launch_bounds__(512, 2) void gemm2(const unsigned short* __restrict__ A,
                                                const unsigned short* __restrict__ Bt,
                                                const float* __restrict__ bias,
                                                float* __restrict__ out) {
  __shared__ __align__(16) unsigned short smem[65536];
  char* sm = (char*)smem;

  const int tid = threadIdx.x;
  const int l   = tid & 63;
  const int w   = tid >> 6;        // wave 0..7
  const int wr  = w >> 2;          // 0..1  (M)
  const int wc  = w & 3;           // 0..3  (N)
  const int l31 = l & 31;
  const int ch  = l >> 5;          // k-half selector
  const int x7  = l & 7;

  // Locality-grouped XCD swizzle (bijective: 8 xcd x 4 g x 5 m x 6 n = 960)
  const int xcd = blockIdx.x & 7;
  const int ii  = blockIdx.x >> 3;
  const int gg  = ii / 30;
  const int rmap= ii % 30;
  const long tM = (long)(gg * 5 + (rmap % 5)) * 256;
  const long tN = (long)(xcd * 6 + (rmap / 5)) * 256;

  // --- staging source (pre-swizzled global address; LDS dest linear) ---
  const int  sRow  = l >> 3;
  const int  sCol8 = ((l & 7) ^ (l >> 3)) * 8;
  const unsigned short* gA2 = A  + (tM + sRow) * (size_t)KPAD + sCol8;
  const unsigned short* gB2 = Bt + (tN + sRow) * (size_t)KPAD + sCol8;

  // 2 loads covering 128 rows of one operand region (bufB = BYTE offset)
  auto stage2 = [&](int bufB, const unsigned short* g, int regionOff) {
    async16(g + (size_t)(w * 8)      * KPAD, (unsigned short*)(sm + bufB + regionOff + w * 1024));
    async16(g + (size_t)(w * 8 + 64) * KPAD, (unsigned short*)(sm + bufB + regionOff + (w + 8) * 1024));
  };

  // --- swizzled read chunk offsets per k-step (chunk = ks*2 + ch, ^ row&7) ---
  const int cofs0 = ((0 + ch) ^ x7) << 4;
  const int cofs1 = ((2 + ch) ^ x7) << 4;
  const int cofs2 = ((4 + ch) ^ x7) << 4;
  const int cofs3 = ((6 + ch) ^ x7) << 4;
  const int aRow  = (wr * 128 + l31) * 128;
  const int bRow  = 32768 + (wc * 64 + l31) * 128;
  const char* pA[2] = { sm + aRow, sm + 65536 + aRow };
  const char* pB[2] = { sm + bRow, sm + 65536 + bRow };

  f32x16 acc[4][2] = {};           // [fm][fn] 32x32 tiles: per-wave 128x64
  bf16x8 af[4][2], bl[2][2], bh[2][2];

  // mode: 0 steady; 1 = t=77 (no stage, vmcnt(0)); 2 = t=78 (tail).
  auto tile = [&](int bi, int mode) {
    const int bo = bi << 16;
    const int ni = bi ^ 1;
    // ==== PH0: read afL(ks0,1) + bh(t); MFMA afL x bl (16) ====
#pragma unroll
    for (int fm = 0; fm < 4; ++fm) {
      af[fm][0] = *(const bf16x8*)(pA[bi] + fm * 4096 + cofs0);
      af[fm][1] = *(const bf16x8*)(pA[bi] + fm * 4096 + cofs1);
    }
#pragma unroll
    for (int fn = 0; fn < 2; ++fn) {
      bh[fn][0] = *(const bf16x8*)(pB[bi] + fn * 4096 + cofs2);
      bh[fn][1] = *(const bf16x8*)(pB[bi] + fn * 4096 + cofs3);
    }
    __builtin_amdgcn_s_setprio(1);
#pragma unroll
    for (int ks = 0; ks < 2; ++ks)
#pragma unroll
      for (int fm = 0; fm < 4; ++fm)
#pragma unroll
        for (int fn = 0; fn < 2; ++fn)
          acc[fm][fn] = __builtin_amdgcn_mfma_f32_32x32x16_bf16(
              af[fm][ks], bl[fn][ks], acc[fm][fn], 0, 0, 0);
    __builtin_amdgcn_s_setprio(0);
    __builtin_amdgcn_s_barrier();
    // ==== PH1: read afH(ks2,3); stage B(t+2) -> bo; MFMA afH(ks2) x bh(ks2) ====
#pragma unroll
    for (int fm = 0; fm < 4; ++fm) {
      af[fm][0] = *(const bf16x8*)(pA[bi] + fm * 4096 + cofs2);
      af[fm][1] = *(const bf16x8*)(pA[bi] + fm * 4096 + cofs3);
    }
    if (mode == 0) {
      stage2(bo, gB2, 32768);
      stage2(bo, gB2 + (size_t)128 * KPAD, 49152);
      gB2 += 64;
    }
    __builtin_amdgcn_s_setprio(1);
#pragma unroll
    for (int fm = 0; fm < 4; ++fm)
#pragma unroll
      for (int fn = 0; fn < 2; ++fn)
        acc[fm][fn] = __builtin_amdgcn_mfma_f32_32x32x16_bf16(
            af[fm][0], bh[fn][0], acc[fm][fn], 0, 0, 0);
    __builtin_amdgcn_s_setprio(0);
    __builtin_amdgcn_s_barrier();
    // ==== PH2: stage A(t+2) -> bo; vmcnt(8); bar; bl(t+1); MFMA afH(ks3) x bh(ks3) ====
    if (mode == 0) {
      stage2(bo, gA2, 0);
      stage2(bo, gA2 + (size_t)128 * KPAD, 16384);
      gA2 += 64;
      asm volatile("s_waitcnt vmcnt(8)" ::: "memory");   // t+1 fully landed
    } else if (mode == 1) {
      asm volatile("s_waitcnt vmcnt(0)" ::: "memory");
    }
    __builtin_amdgcn_s_barrier();                         // globalizes vmcnt
    __builtin_amdgcn_sched_barrier(0);                    // pin reads below
    if (mode != 2) {
#pragma unroll
      for (int fn = 0; fn < 2; ++fn) {
        bl[fn][0] = *(const bf16x8*)(pB[ni] + fn * 4096 + cofs0);  // bl(t+1)
        bl[fn][1] = *(const bf16x8*)(pB[ni] + fn * 4096 + cofs1);
      }
    }
    __builtin_amdgcn_s_setprio(1);
#pragma unroll
    for (int fm = 0; fm < 4; ++fm)
#pragma unroll
      for (int fn = 0; fn < 2; ++fn)
        acc[fm][fn] = __builtin_amdgcn_mfma_f32_32x32x16_bf16(
            af[fm][1], bh[fn][1], acc[fm][fn], 0, 0, 0);
    __builtin_amdgcn_s_setprio(0);
    // no trailing barrier: next PH0's reads are covered by this vmcnt+bar
  };

  // ---- prologue: stage t0 -> buf0, t1 -> buf1; pre-read bl(0) ----
  stage2(0, gB2, 32768); stage2(0, gB2 + (size_t)128 * KPAD, 49152);
  stage2(0, gA2, 0);     stage2(0, gA2 + (size_t)128 * KPAD, 16384);
  gA2 += 64; gB2 += 64;
  stage2(65536, gB2, 32768); stage2(65536, gB2 + (size_t)128 * KPAD, 49152);
  stage2(65536, gA2, 0);     stage2(65536, gA2 + (size_t)128 * KPAD, 16384);
  gA2 += 64; gB2 += 64;       // -> tile 2 (first in-loop stage target)
  asm volatile("s_waitcnt vmcnt(8)" ::: "memory");   // t0's 8 loads retired
  __builtin_amdgcn_s_barrier();
  __builtin_amdgcn_sched_barrier(0);
#pragma unroll
  for (int fn = 0; fn < 2; ++fn) {
    bl[fn][0] = *(const bf16x8*)(pB[0] + fn * 4096 + cofs0);
    bl[fn][1] = *(const bf16x8*)(pB[0] + fn * 4096 + cofs1);
  }

  // ---- main loop: t = 0..78 (79 K-tiles) ----
  for (int it = 0; it < 38; ++it) {    // t = 0..75
    tile(0, 0);
    tile(1, 0);
  }
  tile(0, 0);   // t=76: stages tile 78 into buf0
  tile(1, 1);   // t=77: drain, read bl(78) from buf0
  tile(0, 2);   // t=78: last

  // ---- epilogue: C/D map col=lane&31, row=(reg&3)+8*(reg>>2)+4*(lane>>5) ----
  float bv[2];
#pragma unroll
  for (int fn = 0; fn < 2; ++fn) bv[fn] = bias[fn * 32 + l31];
  const int r0 = ch * 4;
#pragma unroll
  for (int fm = 0; fm < 4; ++fm) {
#pragma unroll
    for (int g = 0; g < 4; ++g) {
      long gmb = tM + wr * 128 + fm * 32 + g * 8 + r0;
#pragma unroll
      for (int r = 0; r < 4; ++r) {
        long gm = gmb + r;
        if (gm < N_VERT) {
          long rowoff = gm * NCOL + tN + wc * 64 + l31;
#pragma unroll
          for (int fn = 0; fn < 2; ++fn)
            out[rowoff + fn * 32] = acc[fm][fn][g * 4 + r] + bv[fn];
        }
      }
    }
  }
}

extern "C" void kernel_launch(void* const* d_in, const int* in_sizes, int n_in,
                              void* d_out, int out_size, void* d_ws, size_t ws_size,
                              hipStream_t stream) {
  const float* x    = (const float*)d_in[0];
  const float* F    = (const float*)d_in[1];
  const float* W    = (const float*)d_in[2];
  const float* bias = (const float*)d_in[3];
  float* out = (float*)d_out;

  const size_t fbB = (size_t)MPAD * KPAD * 2;
  const size_t htB = (size_t)NCOL * KPAD * 2;
  if (ws_size < fbB + htB) return;

  unsigned short* Fb = (unsigned short*)d_ws;
  unsigned short* Ht = (unsigned short*)((char*)d_ws + fbB);

  prep <<<dim3(G1_BLOCKS + CVT_BLOCKS), 256, 0, stream>>>(x, W, F, Ht, Fb);
  gemm2<<<dim3(960),                    512, 0, stream>>>(Fb, Ht, bias, out);
}

// Round 2
// 686.706 us; speedup vs baseline: 1.0689x; 1.0689x over previous
//
#include <hip/hip_runtime.h>

// Problem constants
#define N_VERT 5000
#define NCOL   12288      // B*T*C_OUT reinterpreted columns
#define KPAD   5056       // 79*64: K padded (zero-filled)
#define MPAD   5120       // 20*256: M padded

#define G1_BLOCKS  15168  // 79*192 gemm1 blocks
#define CVT_BLOCKS 25280  // MPAD*(KPAD/4)/256

typedef float          f32x4  __attribute__((ext_vector_type(4)));
typedef unsigned short u16x4  __attribute__((ext_vector_type(4)));
typedef __bf16         bf16x8 __attribute__((ext_vector_type(8)));

__device__ __forceinline__ unsigned short f2bf(float f) {
  unsigned int u = __builtin_bit_cast(unsigned int, f);
  u += 0x7fffu + ((u >> 16) & 1u);   // RNE
  return (unsigned short)(u >> 16);
}

__device__ __forceinline__ void async16(const unsigned short* g, unsigned short* l) {
  __builtin_amdgcn_global_load_lds(
      (const __attribute__((address_space(1))) unsigned int*)g,
      (__attribute__((address_space(3))) unsigned int*)l, 16, 0, 0);
}

// ---------------------------------------------------------------------------
// Kernel P (merged prep): blocks [0, G1_BLOCKS) run GEMM1 (x@W -> Ht = H^T,
// bf16); blocks [G1_BLOCKS, +CVT_BLOCKS) convert F -> Fb bf16 [MPAD][KPAD].
// ---------------------------------------------------------------------------
__global__ __launch_bounds__(256) void prep(const float* __restrict__ x,
                                            const float* __restrict__ W,
                                            const float* __restrict__ F,
                                            unsigned short* __restrict__ Ht,
                                            unsigned short* __restrict__ Fb) {
  __shared__ float xt[64][68];
  __shared__ float Wl[64][68];
  const int tid = threadIdx.x;

  if (blockIdx.x >= G1_BLOCKS) {
    int idx = (blockIdx.x - G1_BLOCKS) * 256 + tid;
    int row = idx / (KPAD / 4);
    int c4  = (idx % (KPAD / 4)) * 4;
    u16x4 o;
    if (row < N_VERT && c4 < N_VERT) {
      f32x4 v = *(const f32x4*)(F + (long)row * N_VERT + c4);
      o.x = f2bf(v.x); o.y = f2bf(v.y); o.z = f2bf(v.z); o.w = f2bf(v.w);
    } else {
      o.x = 0; o.y = 0; o.z = 0; o.w = 0;
    }
    *(u16x4*)(Fb + (long)row * KPAD + c4) = o;
    return;
  }

  const int utile = blockIdx.x % 79;   // 0..78
  const int rr    = blockIdx.x / 79;   // 0..191

  for (int i = tid; i < 4096; i += 256) Wl[i >> 6][i & 63] = W[i];
  {
    int rowu = tid >> 2;
    int cb   = (tid & 3) * 16;
    long u   = (long)utile * 64 + rowu;
    bool valid = (u < N_VERT);
    const float* src = x + (u * 192 + rr) * 64;
#pragma unroll
    for (int q = 0; q < 4; ++q) {
      int col = cb + q * 4;
      f32x4 v = {0.f, 0.f, 0.f, 0.f};
      if (valid) v = *(const f32x4*)(src + col);
      xt[col + 0][rowu] = v.x;
      xt[col + 1][rowu] = v.y;
      xt[col + 2][rowu] = v.z;
      xt[col + 3][rowu] = v.w;
    }
  }
  __syncthreads();

  const int ul0 = (tid & 15) * 4;
  const int j0  = (tid >> 4) * 4;
  float acc[4][4] = {};
#pragma unroll 8
  for (int c = 0; c < 64; ++c) {
    f32x4 xv = *(const f32x4*)&xt[c][ul0];
    f32x4 wv = *(const f32x4*)&Wl[c][j0];
#pragma unroll
    for (int a = 0; a < 4; ++a)
#pragma unroll
      for (int b = 0; b < 4; ++b) acc[a][b] += xv[a] * wv[b];
  }

  long ug = (long)utile * 64 + ul0;
#pragma unroll
  for (int b = 0; b < 4; ++b) {
    long rowh = (long)rr * 64 + (j0 + b);
    u16x4 o = {f2bf(acc[0][b]), f2bf(acc[1][b]), f2bf(acc[2][b]), f2bf(acc[3][b])};
    *(u16x4*)(Ht + rowh * KPAD + ug) = o;
  }
}

// ---------------------------------------------------------------------------
// Kernel 3: GEMM2  agg = F @ H (+bias). 256x256 tile, BK=64, 8 waves (2Mx4N),
// 16x16x32 MFMA (verified fragment/swizzle layout from the R0 kernel).
// *** 8-phase schedule (m201 template): per iter = 2 K-tiles (t->buf0,
// t+1->buf1), 8 phases of {ds-reads; stage 1 half-tile; bar; lgkmcnt(0);
// setprio(1); 16 MFMA; setprio(0); bar}, counted vmcnt(4) only at phases
// 4 and 8. Quadrant order per tile: Q00(A-lo x B-lo), Q01(B-hi), Q11(A-hi),
// Q10 (all frags already in regs). B frags persist across the tile's 4
// phases; A frags reloaded once (mh0 -> mh1).
// Staging per phase (steady state): P1:A-h0(t+1) P2:A-h1(t+1) P3:B-h0(t+2)
// P4:B-h1(t+2) P5:A-h0(t+2) P6:A-h1(t+2) P7:B-h0(t+3) P8:B-h1(t+3).
// Hazards: region's last ds_read completes at its phase's lgkmcnt(0), >=1
// barrier before that region is re-staged (B(buf0) last read P2, staged P3;
// A(buf0) last read P3, staged P5; B(buf1) last read P6, staged P7; A(buf1)
// last read P7 of prev iter, staged P1). vmcnt(4) at P4/P8 end retires all
// 8 loads of the tile consumed 1 phase later (only the newest 2 stage2s
// stay in flight); iter38 drains vmcnt(0) before the no-stage tail tile.
// ---------------------------------------------------------------------------
__global__ __launch_bounds__(512, 2) void gemm2(const unsigned short* __restrict__ A,
                                                const unsigned short* __restrict__ Bt,
                                                const float* __restrict__ bias,
                                                float* __restrict__ out) {
  __shared__ __align__(16) unsigned short smem[65536];
  char* sm = (char*)smem;

  const int tid = threadIdx.x;
  const int l   = tid & 63;
  const int w   = tid >> 6;        // wave 0..7
  const int wr  = w >> 2;          // 0..1  (M)
  const int wc  = w & 3;           // 0..3  (N)
  const int la  = l & 15;

  // Locality-grouped XCD swizzle (bijective: 8 xcd x 4 g x 5 m x 6 n = 960)
  const int xcd = blockIdx.x & 7;
  const int ii  = blockIdx.x >> 3;
  const int gg  = ii / 30;
  const int rmap= ii % 30;
  const long tM = (long)(gg * 5 + (rmap % 5)) * 256;
  const long tN = (long)(xcd * 6 + (rmap / 5)) * 256;

  // --- staging source (pre-swizzled global address; LDS dest linear) ---
  const int  sRow  = l >> 3;
  const int  sCol8 = ((l & 7) ^ (l >> 3)) * 8;
  const unsigned short* gA2 = A  + (tM + sRow) * (size_t)KPAD + sCol8;
  const unsigned short* gB2 = Bt + (tN + sRow) * (size_t)KPAD + sCol8;

  // 2 loads covering 128 rows of one operand half-region (bufB = BYTE offset)
  auto stage2 = [&](int bufB, const unsigned short* g, int regionOff) {
    async16(g + (size_t)(w * 8)      * KPAD, (unsigned short*)(sm + bufB + regionOff + w * 1024));
    async16(g + (size_t)(w * 8 + 64) * KPAD, (unsigned short*)(sm + bufB + regionOff + (w + 8) * 1024));
  };

  // --- hoisted swizzled ds_read base pointers (reads = base + frag*2048) ---
  const int cOff0 = ((l >> 4) * 16)      ^ ((l & 7) << 4);
  const int cOff1 = (64 + (l >> 4) * 16) ^ ((l & 7) << 4);
  const int aRow  = (wr * 128 + la) * 128;
  const int bRow  = 32768 + (wc * 64 + la) * 128;
  const char* pA0[2] = { sm + aRow + cOff0, sm + 65536 + aRow + cOff0 };
  const char* pA1[2] = { sm + aRow + cOff1, sm + 65536 + aRow + cOff1 };
  const char* pB0[2] = { sm + bRow + cOff0, sm + 65536 + bRow + cOff0 };
  const char* pB1[2] = { sm + bRow + cOff1, sm + 65536 + bRow + cOff1 };

  f32x4  acc[8][4] = {};
  bf16x8 aR[4][2], bb[4][2];

#define RD_A(BUF, MH)                                                         \
  _Pragma("unroll")                                                           \
  for (int i = 0; i < 4; ++i) {                                               \
    aR[i][0] = *(const bf16x8*)(pA0[BUF] + ((MH)*4 + i) * 2048);              \
    aR[i][1] = *(const bf16x8*)(pA1[BUF] + ((MH)*4 + i) * 2048);              \
  }
#define RD_B(BUF, NH)                                                         \
  _Pragma("unroll")                                                           \
  for (int j = 0; j < 2; ++j) {                                               \
    bb[(NH)*2 + j][0] = *(const bf16x8*)(pB0[BUF] + ((NH)*2 + j) * 2048);     \
    bb[(NH)*2 + j][1] = *(const bf16x8*)(pB1[BUF] + ((NH)*2 + j) * 2048);     \
  }
#define MM(MH, NH)                                                            \
  __builtin_amdgcn_s_setprio(1);                                              \
  _Pragma("unroll")                                                           \
  for (int ks = 0; ks < 2; ++ks)                                              \
    _Pragma("unroll")                                                         \
    for (int i = 0; i < 4; ++i)                                               \
      _Pragma("unroll")                                                       \
      for (int j = 0; j < 2; ++j)                                             \
        acc[(MH)*4 + i][(NH)*2 + j] = __builtin_amdgcn_mfma_f32_16x16x32_bf16(\
            aR[i][ks], bb[(NH)*2 + j][ks], acc[(MH)*4 + i][(NH)*2 + j],       \
            0, 0, 0);                                                         \
  __builtin_amdgcn_s_setprio(0);
#define BAR __builtin_amdgcn_s_barrier()
#define LG0 asm volatile("s_waitcnt lgkmcnt(0)" ::: "memory")
#define LG8 asm volatile("s_waitcnt lgkmcnt(8)" ::: "memory")

  // ---- prologue: stage t0 -> buf0, t1 -> buf1 (B then A per tile) ----
  stage2(0, gB2, 32768); stage2(0, gB2 + (size_t)128 * KPAD, 49152);
  stage2(0, gA2, 0);     stage2(0, gA2 + (size_t)128 * KPAD, 16384);
  gA2 += 64; gB2 += 64;
  stage2(65536, gB2, 32768); stage2(65536, gB2 + (size_t)128 * KPAD, 49152);
  stage2(65536, gA2, 0);     stage2(65536, gA2 + (size_t)128 * KPAD, 16384);
  gA2 += 64; gB2 += 64;       // -> tile 2 (first in-loop stage target)
  asm volatile("s_waitcnt vmcnt(8)" ::: "memory");   // t0's 8 loads landed
  BAR;

  // ---- one iter = 2 K-tiles, 8 phases ----
  auto cyc = [&](int sA12, int sB78, int drain) {
    // P1: Q00 on buf0; stage A-h0(t+1)
    RD_A(0, 0); RD_B(0, 0);
    if (sA12) stage2(65536, gA2, 0);
    LG8;
    BAR; LG0; MM(0, 0); BAR;
    // P2: Q01; stage A-h1(t+1)
    RD_B(0, 1);
    if (sA12) { stage2(65536, gA2 + (size_t)128 * KPAD, 16384); gA2 += 64; }
    BAR; LG0; MM(0, 1); BAR;
    // P3: Q11; stage B-h0(t+2)  [B(buf0) fully read at P2's lgkmcnt(0)]
    RD_A(0, 1);
    stage2(0, gB2, 32768);
    BAR; LG0; MM(1, 1); BAR;
    // P4: Q10 (no reads); stage B-h1(t+2); vmcnt(4) -> t+1 fully landed
    stage2(0, gB2 + (size_t)128 * KPAD, 49152); gB2 += 64;
    BAR; MM(1, 0);
    asm volatile("s_waitcnt vmcnt(4)" ::: "memory");
    BAR;
    // P5: Q00 on buf1; stage A-h0(t+2)  [A(buf0) fully read at P3]
    RD_A(1, 0); RD_B(1, 0);
    stage2(0, gA2, 0);
    LG8;
    BAR; LG0; MM(0, 0); BAR;
    // P6: Q01; stage A-h1(t+2)
    RD_B(1, 1);
    stage2(0, gA2 + (size_t)128 * KPAD, 16384); gA2 += 64;
    BAR; LG0; MM(0, 1); BAR;
    // P7: Q11; stage B-h0(t+3)  [B(buf1) fully read at P6]
    RD_A(1, 1);
    if (sB78) stage2(65536, gB2, 32768);
    BAR; LG0; MM(1, 1); BAR;
    // P8: Q10; stage B-h1(t+3); vmcnt(4) -> t+2 fully landed
    if (sB78) { stage2(65536, gB2 + (size_t)128 * KPAD, 49152); gB2 += 64; }
    BAR; MM(1, 0);
    if (drain) { asm volatile("s_waitcnt vmcnt(0)" ::: "memory"); }
    else       { asm volatile("s_waitcnt vmcnt(4)" ::: "memory"); }
    BAR;
  };

  // ---- main loop: 39 iters cover t = 0..77 ----
  cyc(0, 1, 0);                                 // iter 0: t1's A staged in prologue
#pragma unroll 1
  for (int i = 1; i < 38; ++i) cyc(1, 1, 0);    // steady
  cyc(1, 0, 1);                                 // iter 38: no t79; drain vmcnt(0)

  // ---- tail: tile 78 in buf0, no staging ----
  RD_A(0, 0); RD_B(0, 0);
  BAR; LG0; MM(0, 0); BAR;
  RD_B(0, 1);
  BAR; LG0; MM(0, 1); BAR;
  RD_A(0, 1);
  BAR; LG0; MM(1, 1); BAR;
  MM(1, 0);

#undef RD_A
#undef RD_B
#undef MM
#undef BAR
#undef LG0
#undef LG8

  // ---- epilogue: C/D map col=lane&15, row=(lane>>4)*4+reg ----
  float bv[4];
#pragma unroll
  for (int n = 0; n < 4; ++n) bv[n] = bias[n * 16 + la];
  const int rb = (l >> 4) * 4;
#pragma unroll
  for (int m = 0; m < 8; ++m) {
    long gm0 = tM + wr * 128 + m * 16 + rb;
#pragma unroll
    for (int rr2 = 0; rr2 < 4; ++rr2) {
      long gm = gm0 + rr2;
      if (gm < N_VERT) {
#pragma unroll
        for (int n = 0; n < 4; ++n) {
          long gn = tN + wc * 64 + n * 16 + la;
          out[gm * NCOL + gn] = acc[m][n][rr2] + bv[n];
        }
      }
    }
  }
}

extern "C" void kernel_launch(void* const* d_in, const int* in_sizes, int n_in,
                              void* d_out, int out_size, void* d_ws, size_t ws_size,
                              hipStream_t stream) {
  const float* x    = (const float*)d_in[0];
  const float* F    = (const float*)d_in[1];
  const float* W    = (const float*)d_in[2];
  const float* bias = (const float*)d_in[3];
  float* out = (float*)d_out;

  const size_t fbB = (size_t)MPAD * KPAD * 2;
  const size_t htB = (size_t)NCOL * KPAD * 2;
  if (ws_size < fbB + htB) return;

  unsigned short* Fb = (unsigned short*)d_ws;
  unsigned short* Ht = (unsigned short*)((char*)d_ws + fbB);

  prep <<<dim3(G1_BLOCKS + CVT_BLOCKS), 256, 0, stream>>>(x, W, F, Ht, Fb);
  gemm2<<<dim3(960),                    512, 0, stream>>>(Fb, Ht, bias, out);
}